// Round 9
// baseline (137.182 us; speedup 1.0000x reference)
//
#include <hip/hip_runtime.h>
#include <math.h>

// VQ-VAE VectorQuantizer forward (MFMA bf16-split formulation), round N+9.
// R8 attribution: ticket finalize was R7's regression; fragment-linear image
// neutral+clean; marginal dispatch ~1.5us (non-main ~64us is fixed overhead).
// VALU audit: ~6000 instrs/wave, 1/3 of K-loop VALU is staging machinery
// (gl_lds addressing + vmcnt/lgkm pacing + dbuf logic) for a 256KB L2-hot
// image (R6 proved L2 BW is not binding; per-CU need ~80GB/s).
// This round, ONE change: DELETE LDS STAGING. A-fragments are read directly
// from the fragment-linear global image via coalesced dwordx4 loads (same
// per-lane addresses gl_lds used). K-loop = clean 64-tile loop, zero asm,
// zero barriers, no sbuf; compiler software-pipelines loads across tiles.
// id = t*4+r (8 bits, ascending-k ties); ecb/phases 0/1/3/4, prep, finalize
// verbatim R8.

typedef __attribute__((ext_vector_type(8))) short short8v;
typedef __attribute__((ext_vector_type(4))) float float4v;
typedef unsigned short u16;
typedef unsigned int u32;

constexpr int D = 64;
constexpr int K = 1024;
constexpr int NPTS = 65536;
constexpr long QOFF = (long)NPTS * D;  // 4194304
constexpr float BIAS = 24.0f;
constexpr float GATE = 5e-3f;  // 2*(split 5e-4 + pack 1e-3) + ref err 2e-4 + margin

// ws layout (16B-aligned sections):
constexpr size_t OFF_LOSS = 0;                               // double
constexpr size_t OFF_CNT  = 256;                             // int[1024]
constexpr size_t OFF_EC   = OFF_CNT + 4096;                  // float[1024] ref-order norms
constexpr size_t OFF_ECB  = OFF_EC + 4096;                   // float[1024] norms + BIAS
constexpr size_t OFF_ET   = OFF_ECB + 4096;                  // float[1024*64] E transposed [k][d]
constexpr size_t OFF_STG  = OFF_ET + (size_t)K * D * 4;      // 256KB fragment-linear image

__device__ __forceinline__ float med3(float a, float b, float c) {
  return __builtin_amdgcn_fmed3f(a, b, c);
}
__device__ __forceinline__ u16 bf16rtn(float x) {
  u32 u = __float_as_uint(x);
  return (u16)((u + 0x7fffu + ((u >> 16) & 1u)) >> 16);
}
__device__ __forceinline__ float bf2f(u16 h) {
  return __uint_as_float(((u32)h) << 16);
}

// ---------------------------------------------------------------------------
// Prep, grid 36 x 256 (VERBATIM R8 — fragment-linear image):
//   blocks 0..31: Et rows + fragment-linear -2E bf16 hi/lo image.
//   blocks 32..35: ref-order ||e_k||^2, eCb, counts/loss zeroing.
// Fragment-linear image: 64 tiles of 16 codes; tile t = k>>4 at byte t*4096;
//   frag f in {0:hi-s0, 1:hi-s1, 2:lo-s0, 3:lo-s1} at f*1024;
//   16B unit for (code k, d-octet q of s-half) at lane (q*16 + (k&15)) * 16.
// A wave's read of a frag (64 lanes x 16B consecutive) is one coalesced 1KB
// access — ideal for direct global dwordx4 loads.
__global__ __launch_bounds__(256) void vq_prep(const float* __restrict__ E,
                                               float* __restrict__ eC,
                                               float* __restrict__ eCb,
                                               float* __restrict__ Et,
                                               unsigned char* __restrict__ stg,
                                               double* __restrict__ lossSum,
                                               int* __restrict__ counts) {
  const int b = blockIdx.x;
  const int tid = threadIdx.x;
  if (b < 32) {
    int gid = b * 256 + tid;
    int k = gid & 1023;        // block covers 256 consecutive k -> coalesced
    int g = gid >> 10;         // d-group 0..7, d = g*8 + j
    float v[8];
#pragma unroll
    for (int j = 0; j < 8; ++j) v[j] = E[(g * 8 + j) * K + k];
    *(float4*)&Et[(size_t)k * 64 + g * 8] = make_float4(v[0], v[1], v[2], v[3]);
    *(float4*)&Et[(size_t)k * 64 + g * 8 + 4] = make_float4(v[4], v[5], v[6], v[7]);
    short8v hv, lv;
#pragma unroll
    for (int j = 0; j < 8; ++j) {
      float m2 = -2.0f * v[j];  // exact
      u16 h = bf16rtn(m2);
      hv[j] = (short)h;
      lv[j] = (short)bf16rtn(m2 - bf2f(h));
    }
    int s = g >> 2, q = g & 3;  // d = s*32 + q*8 + j
    size_t tb = (size_t)(k >> 4) * 4096;
    int lanoff = (q * 16 + (k & 15)) * 16;
    *(short8v*)&stg[tb + (size_t)s * 1024 + lanoff] = hv;        // hi frag
    *(short8v*)&stg[tb + (size_t)(2 + s) * 1024 + lanoff] = lv;  // lo frag
  } else {
    int k = (b - 32) * 256 + tid;  // 0..1023
    float c = __fmul_rn(E[k], E[k]);
#pragma unroll
    for (int d = 1; d < D; ++d) {
      float vv = E[d * K + k];
      c = __fadd_rn(c, __fmul_rn(vv, vv));
    }
    eC[k] = c;
    eCb[k] = c + BIAS;
    counts[k] = 0;
    if (k == 0) *lossSum = 0.0;
  }
}

// ---------------------------------------------------------------------------
// vq_main: no LDS staging — A-fragments direct from L2-resident global image.
__global__ __launch_bounds__(256) void vq_main(const float* __restrict__ x,
                                               const unsigned char* __restrict__ stg,
                                               const float* __restrict__ eC,
                                               const float* __restrict__ eCb,
                                               const float* __restrict__ Etg,
                                               float* __restrict__ out,
                                               double* __restrict__ lossSum,
                                               int* __restrict__ counts) {
  // LDS: ecb 4KB + topbuf 4KB + bkbuf 0.5KB ~= 8.7KB (no staging buffers).
  __shared__ __align__(16) float ecb[1024];
  __shared__ __align__(16) float topbuf[256 * 4];
  __shared__ int bkbuf[128];

  const int tid = threadIdx.x;
  const int w = tid >> 6;        // wave id: owns point-tiles 2w, 2w+1
  const int lane = tid & 63;
  const int col = lane & 15;     // A: code row; B/C: point col
  const int quad = lane >> 4;    // k-group (A/B), row-group (C)
  const int blockBase = blockIdx.x * 128;
  const float INF = __builtin_inff();

  // ---- phase 0: stage all biased norms once (plain LDS copy) ----
  *(float4*)&ecb[tid * 4] = *(const float4*)&eCb[tid * 4];

  // ---- phase 1: load + split x into B-fragments (register-resident) ----
  short8v Bh[2][2], Bl[2][2];
#pragma unroll
  for (int pt = 0; pt < 2; ++pt) {
    const float* xp = x + (size_t)(blockBase + w * 32 + pt * 16 + col) * 64;
#pragma unroll
    for (int s = 0; s < 2; ++s) {
      const float4* src = (const float4*)(xp + s * 32 + quad * 8);
      float4 a = src[0], b = src[1];
      float xs[8] = {a.x, a.y, a.z, a.w, b.x, b.y, b.z, b.w};
      short8v hf, lf;
#pragma unroll
      for (int j = 0; j < 8; ++j) {
        u16 h = bf16rtn(xs[j]);
        hf[j] = (short)h;
        lf[j] = (short)bf16rtn(xs[j] - bf2f(h));
      }
      Bh[pt][s] = hf;
      Bl[pt][s] = lf;
    }
  }

  // one barrier: ecb ds_writes visible to all waves.
  __syncthreads();

  // running top-2 of packed biased distances, per point-tile
  float b1[2] = {INF, INF}, b2[2] = {INF, INF};

  // ---- phase 2: K loop, 64 code-tiles of 16; A-frags direct from global.
  // No barriers, no asm waits, no LDS: compiler pipelines the coalesced
  // dwordx4 loads across iterations (16 waves/CU TLP covers L2 latency).
  const unsigned char* sp = stg + (size_t)lane * 16;
#pragma unroll 2
  for (int t = 0; t < 64; ++t) {
    const unsigned char* fb = sp + (size_t)t * 4096;
    short8v Ah0 = *(const short8v*)(fb);
    short8v Ah1 = *(const short8v*)(fb + 1024);
    short8v Al0 = *(const short8v*)(fb + 2048);
    short8v Al1 = *(const short8v*)(fb + 3072);
    float4v Ci = *(const float4v*)&ecb[t * 16 + quad * 4];
#pragma unroll
    for (int pt = 0; pt < 2; ++pt) {
      // split accumulators: two independent 3-deep MFMA chains per pt
      float4v Ca = Ci;
      float4v Cb = {0.f, 0.f, 0.f, 0.f};
      Ca = __builtin_amdgcn_mfma_f32_16x16x32_bf16(Ah0, Bh[pt][0], Ca, 0, 0, 0);
      Cb = __builtin_amdgcn_mfma_f32_16x16x32_bf16(Ah1, Bh[pt][1], Cb, 0, 0, 0);
      Ca = __builtin_amdgcn_mfma_f32_16x16x32_bf16(Al0, Bh[pt][0], Ca, 0, 0, 0);
      Cb = __builtin_amdgcn_mfma_f32_16x16x32_bf16(Al1, Bh[pt][1], Cb, 0, 0, 0);
      Ca = __builtin_amdgcn_mfma_f32_16x16x32_bf16(Ah0, Bl[pt][0], Ca, 0, 0, 0);
      Cb = __builtin_amdgcn_mfma_f32_16x16x32_bf16(Ah1, Bl[pt][1], Cb, 0, 0, 0);
#pragma unroll
      for (int r = 0; r < 4; ++r) {
        float dv = Ca[r] + Cb[r];
        // pack local id (t:6b | r:2b) into low 8 mantissa bits;
        // k = t*16 + quad*4 + r: ascending (t,r) == ascending k per quad,
        // so fminf ties still resolve toward lower k.
        u32 u = (__float_as_uint(dv) & 0xffffff00u) | (u32)(t * 4 + r);
        float v = __uint_as_float(u);
        float pb = b1[pt];
        b1[pt] = fminf(pb, v);
        b2[pt] = med3(pb, b2[pt], v);
      }
    }
  }

  // ---- phase 3: stash per-lane top-2, merge per point, gate + refine ----
  topbuf[tid * 4 + 0] = b1[0];
  topbuf[tid * 4 + 1] = b2[0];
  topbuf[tid * 4 + 2] = b1[1];
  topbuf[tid * 4 + 3] = b2[1];
  __syncthreads();

  if (tid < 128) {  // one thread per point; tid == point-in-block by construction
    const int mw = tid >> 5, mpt = (tid >> 4) & 1, mcol = tid & 15;
    float cv[8];
    int cq[8];
    float mv0 = INF, mv1 = INF;
    int q0 = 0;
#pragma unroll
    for (int q = 0; q < 4; ++q) {
      int lbase = (mw * 64 + q * 16 + mcol) * 4 + mpt * 2;
#pragma unroll
      for (int j = 0; j < 2; ++j) {
        float v = topbuf[lbase + j];
        cv[q * 2 + j] = v;
        cq[q * 2 + j] = q;
        if (v < mv0) { mv1 = mv0; mv0 = v; q0 = q; }
        else if (v < mv1) { mv1 = v; }
      }
    }
    u32 lb = __float_as_uint(mv0) & 255u;
    // id = t*4 + r ; k = t*16 + quad*4 + r
    int bestk = (int)((lb >> 2) * 16 + q0 * 4 + (lb & 3));

    if (mv1 - mv0 < GATE) {
      // ----- exact emulation of the np reference's fp32 arithmetic -----
      const float* f = x + (size_t)(blockBase + tid) * 64;
      float r8[8];
#pragma unroll
      for (int j = 0; j < 8; ++j) { float fv = f[j]; r8[j] = __fmul_rn(fv, fv); }
#pragma unroll
      for (int i = 8; i < D; i += 8)
#pragma unroll
        for (int j = 0; j < 8; ++j) {
          float fv = f[i + j];
          r8[j] = __fadd_rn(r8[j], __fmul_rn(fv, fv));
        }
      float A = __fadd_rn(__fadd_rn(__fadd_rn(r8[0], r8[1]), __fadd_rn(r8[2], r8[3])),
                          __fadd_rn(__fadd_rn(r8[4], r8[5]), __fadd_rn(r8[6], r8[7])));
      float bd = INF;
      int bkk = K;
#pragma unroll
      for (int c = 0; c < 8; ++c) {
        u32 cb = __float_as_uint(cv[c]) & 255u;
        int k = (int)((cb >> 2) * 16 + cq[c] * 4 + (cb & 3));
        // Et row is d-ascending -> identical fp32 fma sequence, contiguous loads
        const float* er = Etg + (size_t)k * 64;
        float m = 0.f;
#pragma unroll
        for (int d = 0; d < D; ++d) m = __fmaf_rn(f[d], er[d], m);
        float dist = __fadd_rn(__fsub_rn(A, __fmul_rn(2.f, m)), eC[k]);
        bool better = (dist < bd) || (dist == bd && k < bkk);
        bd = better ? dist : bd;
        bkk = better ? k : bkk;
      }
      bestk = bkk;
    }

    bkbuf[tid] = bestk;
    out[QOFF + 2 + blockBase + tid] = (float)bestk;  // index (exact as float)
    atomicAdd(&counts[bestk], 1);
  }
  __syncthreads();

  // ---- phase 4: quantized write (gather from Et, coalesced) + loss ----
  const int pp = tid >> 1, half = tid & 1;
  const int bk = bkbuf[pp];
  const float4* et = (const float4*)(Etg + (size_t)bk * 64 + half * 32);
  const float4* xr = (const float4*)(x + (size_t)(blockBase + pp) * 64 + half * 32);
  float4* ov = (float4*)(out + (size_t)(blockBase + pp) * 64 + half * 32);
  float errs = 0.f;
#pragma unroll
  for (int i = 0; i < 8; ++i) {
    float4 qv = et[i];
    float4 xv = xr[i];
    float dx;
    dx = qv.x - xv.x; errs = fmaf(dx, dx, errs);
    dx = qv.y - xv.y; errs = fmaf(dx, dx, errs);
    dx = qv.z - xv.z; errs = fmaf(dx, dx, errs);
    dx = qv.w - xv.w; errs = fmaf(dx, dx, errs);
    ov[i] = qv;
  }
  double de = (double)errs;
#pragma unroll
  for (int off = 32; off > 0; off >>= 1) de += __shfl_down(de, off, 64);
  if (lane == 0) atomicAdd(lossSum, de);
}

__global__ __launch_bounds__(256) void vq_finalize(const double* __restrict__ lossSum,
                                                   const int* __restrict__ counts,
                                                   float* __restrict__ out) {
  __shared__ double sh[256];
  double ent = 0.0;
  for (int k = threadIdx.x; k < K; k += 256) {
    double pp = (double)counts[k] / (double)NPTS;
    ent += pp * log(pp + 1e-10);
  }
  sh[threadIdx.x] = ent;
  __syncthreads();
  for (int s = 128; s > 0; s >>= 1) {
    if (threadIdx.x < s) sh[threadIdx.x] += sh[threadIdx.x + s];
    __syncthreads();
  }
  if (threadIdx.x == 0) {
    // loss = q_latent + 0.25 * e_latent = 1.25 * mean((q - x)^2)
    out[QOFF + 0] = (float)(1.25 * (*lossSum) / (double)((long)NPTS * D));
    out[QOFF + 1] = (float)exp(-sh[0]);  // perplexity
  }
}

extern "C" void kernel_launch(void* const* d_in, const int* in_sizes, int n_in,
                              void* d_out, int out_size, void* d_ws, size_t ws_size,
                              hipStream_t stream) {
  const float* x = (const float*)d_in[0];
  const float* E = (const float*)d_in[1];
  float* out = (float*)d_out;

  char* ws = (char*)d_ws;
  double* lossSum = (double*)(ws + OFF_LOSS);
  int* counts = (int*)(ws + OFF_CNT);
  float* eC = (float*)(ws + OFF_EC);
  float* eCb = (float*)(ws + OFF_ECB);
  float* Etg = (float*)(ws + OFF_ET);
  unsigned char* stgb = (unsigned char*)(ws + OFF_STG);

  // prep zeroes lossSum/counts itself (ws is poisoned before every timed
  // launch); no memset dispatch needed.
  vq_prep<<<36, 256, 0, stream>>>(E, eC, eCb, Etg, stgb, lossSum, counts);
  vq_main<<<NPTS / 128, 256, 0, stream>>>(x, stgb, eC, eCb, Etg, out,
                                          lossSum, counts);
  vq_finalize<<<1, 256, 0, stream>>>(lossSum, counts, out);
}

// Round 10
// 130.407 us; speedup vs baseline: 1.0520x; 1.0520x over previous
//
#include <hip/hip_runtime.h>
#include <math.h>

// VQ-VAE VectorQuantizer forward (MFMA bf16-split formulation), round N+10.
// R9 lesson: LDS staging IS functioning prefetch (direct-global regressed
// 65->71; R8 structure is main's plateau at ~64.9us after 6 attempts).
// R0-vs-R8 ledger: non-main 44.3us (R0: memset+norm4+conv64+finalize, 5
// dispatches) vs 64.1us (R8: prep36+finalize, 3 dispatches) -> prep36 itself
// costs ~25us (half the parallelism of R0's conv on a latency-bound
// transpose-scatter + divergent fused norm).
// This round, ONE change: prep reverted to R0's proven grid shape —
//   vq_conv 64x256 (work item = (k, dg of 4 dims): 4 strided E loads, Et
//   float4 write, fragment-linear hi/lo 8B writes, bit-identical image) +
//   vq_norm 4x256 (ref-order norms + counts/loss zeroing; no memset).
// vq_main + vq_finalize VERBATIM R8 (best measured: 64.9us main, 129.0 total).

typedef __attribute__((ext_vector_type(8))) short short8v;
typedef __attribute__((ext_vector_type(4))) float float4v;
typedef unsigned short u16;
typedef unsigned int u32;

constexpr int D = 64;
constexpr int K = 1024;
constexpr int NPTS = 65536;
constexpr long QOFF = (long)NPTS * D;  // 4194304
constexpr float BIAS = 24.0f;
constexpr float GATE = 5e-3f;  // 2*(split 5e-4 + pack 1e-3) + ref err 2e-4 + margin

// ws layout (16B-aligned sections):
constexpr size_t OFF_LOSS = 0;                               // double
constexpr size_t OFF_CNT  = 256;                             // int[1024]
constexpr size_t OFF_EC   = OFF_CNT + 4096;                  // float[1024] ref-order norms
constexpr size_t OFF_ECB  = OFF_EC + 4096;                   // float[1024] norms + BIAS
constexpr size_t OFF_ET   = OFF_ECB + 4096;                  // float[1024*64] E transposed [k][d]
constexpr size_t OFF_STG  = OFF_ET + (size_t)K * D * 4;      // 256KB fragment-linear image

__device__ __forceinline__ float med3(float a, float b, float c) {
  return __builtin_amdgcn_fmed3f(a, b, c);
}
__device__ __forceinline__ u16 bf16rtn(float x) {
  u32 u = __float_as_uint(x);
  return (u16)((u + 0x7fffu + ((u >> 16) & 1u)) >> 16);
}
__device__ __forceinline__ float bf2f(u16 h) {
  return __uint_as_float(((u32)h) << 16);
}
// async global->LDS, 16B per lane; dest must be wave-uniform base + lane*16.
__device__ __forceinline__ void gl_lds16(const void* g, void* l) {
  __builtin_amdgcn_global_load_lds(
      (const __attribute__((address_space(1))) u32*)g,
      (__attribute__((address_space(3))) u32*)l, 16, 0, 0);
}

// ---------------------------------------------------------------------------
// Conv, grid 64 x 256 (R0's proven work mapping: 16384 threads, 4 elems each):
// thread <-> (k = gid&1023, dg = gid>>10 in 0..15; d = dg*4 + i).
// Writes Et row quads + fragment-linear -2E bf16 hi/lo image (bit-identical
// bytes to R8's image):
//   tile t = k>>4 at t*4096; frag {0:hi-s0,1:hi-s1,2:lo-s0,3:lo-s1} at f*1024;
//   16B unit for (k, d-octet q of s-half) at (q*16 + (k&15))*16, elem j at +2j.
__global__ __launch_bounds__(256) void vq_conv(const float* __restrict__ E,
                                               float* __restrict__ Et,
                                               unsigned char* __restrict__ stg) {
  int gid = blockIdx.x * 256 + threadIdx.x;  // 16384
  int k = gid & 1023;   // coalesced over k within a wave
  int dg = gid >> 10;   // 0..15
  float v[4];
#pragma unroll
  for (int i = 0; i < 4; ++i) v[i] = E[(dg * 4 + i) * K + k];
  *(float4*)&Et[(size_t)k * 64 + dg * 4] = make_float4(v[0], v[1], v[2], v[3]);
  u16 h[4], l[4];
#pragma unroll
  for (int i = 0; i < 4; ++i) {
    float m2 = -2.0f * v[i];  // exact
    h[i] = bf16rtn(m2);
    l[i] = bf16rtn(m2 - bf2f(h[i]));
  }
  // d = dg*4+i = s*32 + q*8 + (jb + i):  s = dg>>3, q = (dg>>1)&3, jb = (dg&1)*4
  int s = dg >> 3, q = (dg >> 1) & 3, jb = (dg & 1) * 4;
  size_t base = (size_t)(k >> 4) * 4096 + (size_t)s * 1024 +
                (size_t)((q * 16 + (k & 15)) * 16) + (size_t)(jb * 2);
  ushort4 hv = {h[0], h[1], h[2], h[3]};
  ushort4 lv = {l[0], l[1], l[2], l[3]};
  *(ushort4*)&stg[base] = hv;           // hi frag (f = s)
  *(ushort4*)&stg[base + 2048] = lv;    // lo frag (f = 2+s)
}

// Norm, grid 4 x 256: ref-order ||e_k||^2 (strict sequential fp32 over d
// ascending) + eCb + counts/loss zeroing (ws poisoned before every launch).
__global__ __launch_bounds__(256) void vq_norm(const float* __restrict__ E,
                                               float* __restrict__ eC,
                                               float* __restrict__ eCb,
                                               double* __restrict__ lossSum,
                                               int* __restrict__ counts) {
  int k = blockIdx.x * 256 + threadIdx.x;  // 0..1023
  float c = __fmul_rn(E[k], E[k]);
#pragma unroll
  for (int d = 1; d < D; ++d) {
    float vv = E[d * K + k];
    c = __fadd_rn(c, __fmul_rn(vv, vv));
  }
  eC[k] = c;
  eCb[k] = c + BIAS;
  counts[k] = 0;
  if (k == 0) *lossSum = 0.0;
}

// ---------------------------------------------------------------------------
// VERBATIM R8 vq_main (measured 64.9us): wave-private zero-barrier K-loop,
// fragment-linear lane-linear ds_reads, gl_lds double-buffer, vmcnt pacing.
__global__ __launch_bounds__(256) void vq_main(const float* __restrict__ x,
                                               const unsigned char* __restrict__ stg,
                                               const float* __restrict__ eC,
                                               const float* __restrict__ eCb,
                                               const float* __restrict__ Etg,
                                               float* __restrict__ out,
                                               double* __restrict__ lossSum,
                                               int* __restrict__ counts) {
  // Wave-private staging: sbuf[wave][buf] 8KB each = 64KB; + ecb 4KB +
  // topbuf 4KB + bkbuf -> ~72.7KB => 2 blocks/CU.
  __shared__ __align__(16) unsigned char sbuf[4][2][8192];
  __shared__ __align__(16) float ecb[1024];
  __shared__ __align__(16) float topbuf[256 * 4];
  __shared__ int bkbuf[128];

  const int tid = threadIdx.x;
  const int w = tid >> 6;        // wave id: owns point-tiles 2w, 2w+1
  const int lane = tid & 63;
  const int col = lane & 15;     // A: code row; B/C: point col
  const int quad = lane >> 4;    // k-group (A/B), row-group (C)
  const int blockBase = blockIdx.x * 128;
  const float INF = __builtin_inff();

  // ---- phase 0: stage all biased norms once (plain LDS copy) ----
  *(float4*)&ecb[tid * 4] = *(const float4*)&eCb[tid * 4];

  // ---- phase 1: load + split x into B-fragments (register-resident) ----
  short8v Bh[2][2], Bl[2][2];
#pragma unroll
  for (int pt = 0; pt < 2; ++pt) {
    const float* xp = x + (size_t)(blockBase + w * 32 + pt * 16 + col) * 64;
#pragma unroll
    for (int s = 0; s < 2; ++s) {
      const float4* src = (const float4*)(xp + s * 32 + quad * 8);
      float4 a = src[0], b = src[1];
      float xs[8] = {a.x, a.y, a.z, a.w, b.x, b.y, b.z, b.w};
      short8v hf, lf;
#pragma unroll
      for (int j = 0; j < 8; ++j) {
        u16 h = bf16rtn(xs[j]);
        hf[j] = (short)h;
        lf[j] = (short)bf16rtn(xs[j] - bf2f(h));
      }
      Bh[pt][s] = hf;
      Bl[pt][s] = lf;
    }
  }

  // ---- prologue: this wave stages mini-chunks 0 and 1 into its own bufs ----
  {
    const unsigned char* s0 = stg + (size_t)lane * 16;
#pragma unroll
    for (int i = 0; i < 8; ++i)
      gl_lds16(s0 + i * 1024, &sbuf[w][0][i * 1024 + lane * 16]);
#pragma unroll
    for (int i = 0; i < 8; ++i)
      gl_lds16(s0 + 8192 + i * 1024, &sbuf[w][1][i * 1024 + lane * 16]);
  }
  // ONE barrier: ecb ds_writes visible to all waves. No vmcnt drain — the
  // 16 staged loads stay in flight (wave-private, paced by vmcnt below).
  asm volatile("s_waitcnt lgkmcnt(0)" ::: "memory");
  __builtin_amdgcn_s_barrier();
  __builtin_amdgcn_sched_barrier(0);
  asm volatile("" ::: "memory");

  // running top-2 of packed biased distances, per point-tile
  float b1[2] = {INF, INF}, b2[2] = {INF, INF};

  // ---- phase 2: K loop, 32 wave-private mini-chunks of 32 codes ----
  // Zero barriers: each wave reads only LDS it staged itself; double-buffer
  // paced by counted vmcnt (issue ch+2, wait ch via vmcnt(8)).
#pragma unroll 1
  for (int ch = 0; ch < 32; ++ch) {
    const unsigned char* bufB = sbuf[w][ch & 1];
    if (ch < 31) {
      asm volatile("s_waitcnt vmcnt(8)" ::: "memory");   // ch landed; ch+1 may fly
    } else {
      asm volatile("s_waitcnt vmcnt(0)" ::: "memory");   // last chunk landed
    }
#pragma unroll
    for (int ct2 = 0; ct2 < 2; ++ct2) {  // 2 code-tiles of 16
      // fragment-linear: lane-linear 16B units, conflict-free ds_read_b128
      const unsigned char* fb = bufB + ct2 * 4096 + lane * 16;
      short8v Ah0 = *(const short8v*)(fb);
      short8v Ah1 = *(const short8v*)(fb + 1024);
      short8v Al0 = *(const short8v*)(fb + 2048);
      short8v Al1 = *(const short8v*)(fb + 3072);
      float4v Ci = *(const float4v*)&ecb[ch * 32 + ct2 * 16 + quad * 4];
#pragma unroll
      for (int pt = 0; pt < 2; ++pt) {
        // split accumulators: two independent 3-deep MFMA chains per pt
        float4v Ca = Ci;
        float4v Cb = {0.f, 0.f, 0.f, 0.f};
        Ca = __builtin_amdgcn_mfma_f32_16x16x32_bf16(Ah0, Bh[pt][0], Ca, 0, 0, 0);
        Cb = __builtin_amdgcn_mfma_f32_16x16x32_bf16(Ah1, Bh[pt][1], Cb, 0, 0, 0);
        Ca = __builtin_amdgcn_mfma_f32_16x16x32_bf16(Al0, Bh[pt][0], Ca, 0, 0, 0);
        Cb = __builtin_amdgcn_mfma_f32_16x16x32_bf16(Al1, Bh[pt][1], Cb, 0, 0, 0);
        Ca = __builtin_amdgcn_mfma_f32_16x16x32_bf16(Ah0, Bl[pt][0], Ca, 0, 0, 0);
        Cb = __builtin_amdgcn_mfma_f32_16x16x32_bf16(Ah1, Bl[pt][1], Cb, 0, 0, 0);
#pragma unroll
        for (int r = 0; r < 4; ++r) {
          float dv = Ca[r] + Cb[r];
          // pack local id (ch:5b | ct2:1b | r:2b) into low 8 mantissa bits;
          // (ch,ct2,r) lexicographic == ascending k for fixed quad => ties
          // still resolve toward lower k.
          u32 u = (__float_as_uint(dv) & 0xffffff00u) |
                  (u32)(ch * 8 + ct2 * 4 + r);
          float v = __uint_as_float(u);
          float pb = b1[pt];
          b1[pt] = fminf(pb, v);
          b2[pt] = med3(pb, b2[pt], v);
        }
      }
    }
    // my ds_reads of bufB delivered (wave-local), then overwrite with ch+2.
    asm volatile("s_waitcnt lgkmcnt(0)" ::: "memory");
    if (ch < 30) {
      const unsigned char* s2 = stg + (size_t)(ch + 2) * 8192 + (size_t)lane * 16;
#pragma unroll
      for (int i = 0; i < 8; ++i)
        gl_lds16(s2 + i * 1024, &sbuf[w][ch & 1][i * 1024 + lane * 16]);
    }
  }

  // ---- phase 3: stash per-lane top-2, merge per point, gate + refine ----
  topbuf[tid * 4 + 0] = b1[0];
  topbuf[tid * 4 + 1] = b2[0];
  topbuf[tid * 4 + 2] = b1[1];
  topbuf[tid * 4 + 3] = b2[1];
  __syncthreads();

  if (tid < 128) {  // one thread per point; tid == point-in-block by construction
    const int mw = tid >> 5, mpt = (tid >> 4) & 1, mcol = tid & 15;
    float cv[8];
    int cq[8];
    float mv0 = INF, mv1 = INF;
    int q0 = 0;
#pragma unroll
    for (int q = 0; q < 4; ++q) {
      int lbase = (mw * 64 + q * 16 + mcol) * 4 + mpt * 2;
#pragma unroll
      for (int j = 0; j < 2; ++j) {
        float v = topbuf[lbase + j];
        cv[q * 2 + j] = v;
        cq[q * 2 + j] = q;
        if (v < mv0) { mv1 = mv0; mv0 = v; q0 = q; }
        else if (v < mv1) { mv1 = v; }
      }
    }
    u32 lb = __float_as_uint(mv0) & 255u;
    // id = ch*8 + ct2*4 + r ; k = ch*32 + ct2*16 + quad*4 + r
    int bestk = (int)((lb >> 3) * 32 + ((lb >> 2) & 1) * 16 + q0 * 4 + (lb & 3));

    if (mv1 - mv0 < GATE) {
      // ----- exact emulation of the np reference's fp32 arithmetic -----
      const float* f = x + (size_t)(blockBase + tid) * 64;
      float r8[8];
#pragma unroll
      for (int j = 0; j < 8; ++j) { float fv = f[j]; r8[j] = __fmul_rn(fv, fv); }
#pragma unroll
      for (int i = 8; i < D; i += 8)
#pragma unroll
        for (int j = 0; j < 8; ++j) {
          float fv = f[i + j];
          r8[j] = __fadd_rn(r8[j], __fmul_rn(fv, fv));
        }
      float A = __fadd_rn(__fadd_rn(__fadd_rn(r8[0], r8[1]), __fadd_rn(r8[2], r8[3])),
                          __fadd_rn(__fadd_rn(r8[4], r8[5]), __fadd_rn(r8[6], r8[7])));
      float bd = INF;
      int bkk = K;
#pragma unroll
      for (int c = 0; c < 8; ++c) {
        u32 cb = __float_as_uint(cv[c]) & 255u;
        int k = (int)((cb >> 3) * 32 + ((cb >> 2) & 1) * 16 + cq[c] * 4 + (cb & 3));
        // Et row is d-ascending -> identical fp32 fma sequence, contiguous loads
        const float* er = Etg + (size_t)k * 64;
        float m = 0.f;
#pragma unroll
        for (int d = 0; d < D; ++d) m = __fmaf_rn(f[d], er[d], m);
        float dist = __fadd_rn(__fsub_rn(A, __fmul_rn(2.f, m)), eC[k]);
        bool better = (dist < bd) || (dist == bd && k < bkk);
        bd = better ? dist : bd;
        bkk = better ? k : bkk;
      }
      bestk = bkk;
    }

    bkbuf[tid] = bestk;
    out[QOFF + 2 + blockBase + tid] = (float)bestk;  // index (exact as float)
    atomicAdd(&counts[bestk], 1);
  }
  __syncthreads();

  // ---- phase 4: quantized write (gather from Et, coalesced) + loss ----
  const int pp = tid >> 1, half = tid & 1;
  const int bk = bkbuf[pp];
  const float4* et = (const float4*)(Etg + (size_t)bk * 64 + half * 32);
  const float4* xr = (const float4*)(x + (size_t)(blockBase + pp) * 64 + half * 32);
  float4* ov = (float4*)(out + (size_t)(blockBase + pp) * 64 + half * 32);
  float errs = 0.f;
#pragma unroll
  for (int i = 0; i < 8; ++i) {
    float4 qv = et[i];
    float4 xv = xr[i];
    float dx;
    dx = qv.x - xv.x; errs = fmaf(dx, dx, errs);
    dx = qv.y - xv.y; errs = fmaf(dx, dx, errs);
    dx = qv.z - xv.z; errs = fmaf(dx, dx, errs);
    dx = qv.w - xv.w; errs = fmaf(dx, dx, errs);
    ov[i] = qv;
  }
  double de = (double)errs;
#pragma unroll
  for (int off = 32; off > 0; off >>= 1) de += __shfl_down(de, off, 64);
  if (lane == 0) atomicAdd(lossSum, de);
}

__global__ __launch_bounds__(256) void vq_finalize(const double* __restrict__ lossSum,
                                                   const int* __restrict__ counts,
                                                   float* __restrict__ out) {
  __shared__ double sh[256];
  double ent = 0.0;
  for (int k = threadIdx.x; k < K; k += 256) {
    double pp = (double)counts[k] / (double)NPTS;
    ent += pp * log(pp + 1e-10);
  }
  sh[threadIdx.x] = ent;
  __syncthreads();
  for (int s = 128; s > 0; s >>= 1) {
    if (threadIdx.x < s) sh[threadIdx.x] += sh[threadIdx.x + s];
    __syncthreads();
  }
  if (threadIdx.x == 0) {
    // loss = q_latent + 0.25 * e_latent = 1.25 * mean((q - x)^2)
    out[QOFF + 0] = (float)(1.25 * (*lossSum) / (double)((long)NPTS * D));
    out[QOFF + 1] = (float)exp(-sh[0]);  // perplexity
  }
}

extern "C" void kernel_launch(void* const* d_in, const int* in_sizes, int n_in,
                              void* d_out, int out_size, void* d_ws, size_t ws_size,
                              hipStream_t stream) {
  const float* x = (const float*)d_in[0];
  const float* E = (const float*)d_in[1];
  float* out = (float*)d_out;

  char* ws = (char*)d_ws;
  double* lossSum = (double*)(ws + OFF_LOSS);
  int* counts = (int*)(ws + OFF_CNT);
  float* eC = (float*)(ws + OFF_EC);
  float* eCb = (float*)(ws + OFF_ECB);
  float* Etg = (float*)(ws + OFF_ET);
  unsigned char* stgb = (unsigned char*)(ws + OFF_STG);

  // norm zeroes lossSum/counts (ws is poisoned before every timed launch);
  // no memset dispatch needed.
  vq_conv<<<64, 256, 0, stream>>>(E, Etg, stgb);
  vq_norm<<<4, 256, 0, stream>>>(E, eC, eCb, lossSum, counts);
  vq_main<<<NPTS / 128, 256, 0, stream>>>(x, stgb, eC, eCb, Etg, out,
                                          lossSum, counts);
  vq_finalize<<<1, 256, 0, stream>>>(lossSum, counts, out);
}